// Round 1
// baseline (281.809 us; speedup 1.0000x reference)
//
#include <hip/hip_runtime.h>
#include <hip/hip_bf16.h>

#define SEQLEN 4096

typedef __bf16 bf16x8 __attribute__((ext_vector_type(8)));
typedef float f32x4 __attribute__((ext_vector_type(4)));
typedef __attribute__((ext_vector_type(8))) unsigned short u16x8;

__device__ inline float bf2f(unsigned short s) {
  union { unsigned u; float f; } t; t.u = ((unsigned)s) << 16; return t.f;
}
__device__ inline unsigned short f2bf(float f) {
  __hip_bfloat16 h = __float2bfloat16(f);
  return *reinterpret_cast<unsigned short*>(&h);
}

__device__ inline void gload_lds16(const void* g, void* l) {
  __builtin_amdgcn_global_load_lds(
      (const __attribute__((address_space(1))) unsigned int*)g,
      (__attribute__((address_space(3))) unsigned int*)l, 16, 0, 0);
}

// ---------------- conversion kernels ----------------
__global__ void cvt_f32_to_bf16(const float* __restrict__ s,
                                unsigned short* __restrict__ d, int n4) {
  int i = blockIdx.x * 256 + threadIdx.x;
  if (i >= n4) return;
  float4 v = reinterpret_cast<const float4*>(s)[i];
  ushort4 o;
  o.x = f2bf(v.x); o.y = f2bf(v.y); o.z = f2bf(v.z); o.w = f2bf(v.w);
  reinterpret_cast<ushort4*>(d)[i] = o;
}

__global__ void pack_bias(const float* __restrict__ a, const float* __restrict__ b,
                          const float* __restrict__ c, float* __restrict__ dst) {
  int i = blockIdx.x * 256 + threadIdx.x;
  if (i < 1024) { dst[i] = a[i]; dst[1024 + i] = b[i]; dst[2048 + i] = c[i]; }
}

// ---------------- m97-style bf16 GEMM: C = A @ B^T + bias ----------------
// A: [M][K] bf16 (ushort), B: [N][K] bf16 (B^T layout = torch weight row-major)
// OUT_T: unsigned short (bf16) or float
template <typename OUT_T>
__global__ void gemm_bt(const unsigned short* __restrict__ A,
                        const unsigned short* __restrict__ B,
                        const float* __restrict__ bias, OUT_T* __restrict__ C,
                        int M, int N, int K, int ldc) {
  __shared__ __align__(16) unsigned short As[128 * 64];
  __shared__ __align__(16) unsigned short Bs[128 * 64];
  const int tid = threadIdx.x;
  const int lane = tid & 63, wv = tid >> 6;
  const int wr = wv >> 1, wc = wv & 1;
  const int r16 = lane & 15, kg = lane >> 4;
  const int brow = blockIdx.y * 128, bcol = blockIdx.x * 128;

  f32x4 acc[4][4];
#pragma unroll
  for (int m = 0; m < 4; ++m)
#pragma unroll
    for (int n = 0; n < 4; ++n) acc[m][n] = (f32x4)0.0f;

  for (int k0 = 0; k0 < K; k0 += 64) {
#pragma unroll
    for (int it = 0; it < 4; ++it) {
      int f = it * 256 + tid;
      int row = f >> 3, ch = f & 7;
      const unsigned short* ga = A + (size_t)(brow + row) * K + k0 + ch * 8;
      const unsigned short* gb = B + (size_t)(bcol + row) * K + k0 + ch * 8;
      gload_lds16(ga, &As[f * 8]);
      gload_lds16(gb, &Bs[f * 8]);
    }
    __syncthreads();
#pragma unroll
    for (int ks = 0; ks < 2; ++ks) {
      bf16x8 a[4], b[4];
#pragma unroll
      for (int m = 0; m < 4; ++m)
        a[m] = *reinterpret_cast<const bf16x8*>(
            &As[(wr * 64 + m * 16 + r16) * 64 + ks * 32 + kg * 8]);
#pragma unroll
      for (int n = 0; n < 4; ++n)
        b[n] = *reinterpret_cast<const bf16x8*>(
            &Bs[(wc * 64 + n * 16 + r16) * 64 + ks * 32 + kg * 8]);
#pragma unroll
      for (int m = 0; m < 4; ++m)
#pragma unroll
        for (int n = 0; n < 4; ++n)
          acc[m][n] =
              __builtin_amdgcn_mfma_f32_16x16x32_bf16(a[m], b[n], acc[m][n], 0, 0, 0);
    }
    __syncthreads();
  }

#pragma unroll
  for (int n = 0; n < 4; ++n) {
    int col = bcol + wc * 64 + n * 16 + r16;
    float bv = bias ? bias[col] : 0.0f;
#pragma unroll
    for (int m = 0; m < 4; ++m) {
#pragma unroll
      for (int r = 0; r < 4; ++r) {
        int row = brow + wr * 64 + m * 16 + kg * 4 + r;
        float v = acc[m][n][r] + bv;
        if constexpr (sizeof(OUT_T) == 2) {
          C[(size_t)row * ldc + col] = f2bf(v);
        } else {
          C[(size_t)row * ldc + col] = v;
        }
      }
    }
  }
}

// ---------------- k_lin / v_lin partial sums ----------------
// k_lin[b,h,k,d] = sum_n E[h,k,n] * K[b,n,h*64+d]   (K,V from QKV buffer)
// grid: 512 blocks = (bh 0..63) x (ns 0..7); each covers 512 n in 4 chunks of 128
__global__ void kvlin_part(const unsigned short* __restrict__ qkv,
                           const float* __restrict__ E, const float* __restrict__ F,
                           float* __restrict__ part) {
  __shared__ __align__(16) unsigned short Ks[128 * 64], Vs[128 * 64];
  __shared__ __align__(16) float Es[16 * 128], Fs[16 * 128];
  const int tid = threadIdx.x;
  const int bid = blockIdx.x;
  const int bh = bid >> 3, ns = bid & 7;
  const int b = bh >> 4, h = bh & 15;
  const int d = tid & 63, kk = tid >> 6;  // kk: 0..3 -> k = kk*4+j
  float aK[4] = {0, 0, 0, 0}, aV[4] = {0, 0, 0, 0};
  for (int c = 0; c < 4; ++c) {
    int n0 = ns * 512 + c * 128;
#pragma unroll
    for (int it = 0; it < 4; ++it) {
      int f = it * 256 + tid;
      int row = f >> 3, ch = f & 7;
      const unsigned short* gk =
          qkv + (size_t)(b * SEQLEN + n0 + row) * 3072 + 1024 + h * 64 + ch * 8;
      gload_lds16(gk, &Ks[f * 8]);
      gload_lds16(gk + 1024, &Vs[f * 8]);
    }
#pragma unroll
    for (int it = 0; it < 2; ++it) {
      int f = it * 256 + tid;
      int k = f >> 5, ch = f & 31;
      const float* ge = E + (size_t)(h * 16 + k) * SEQLEN + n0 + ch * 4;
      const float* gf = F + (size_t)(h * 16 + k) * SEQLEN + n0 + ch * 4;
      gload_lds16(ge, &Es[f * 4]);
      gload_lds16(gf, &Fs[f * 4]);
    }
    __syncthreads();
    for (int n = 0; n < 128; ++n) {
      float kv = bf2f(Ks[n * 64 + d]);
      float vv = bf2f(Vs[n * 64 + d]);
#pragma unroll
      for (int j = 0; j < 4; ++j) {
        aK[j] += Es[(kk * 4 + j) * 128 + n] * kv;
        aV[j] += Fs[(kk * 4 + j) * 128 + n] * vv;
      }
    }
    __syncthreads();
  }
  size_t base = ((size_t)ns * 64 + bh) * 2048;
#pragma unroll
  for (int j = 0; j < 4; ++j) {
    part[base + (kk * 4 + j) * 64 + d] = aK[j];
    part[base + 1024 + (kk * 4 + j) * 64 + d] = aV[j];
  }
}

__global__ void kvlin_reduce(const float* __restrict__ part, float* __restrict__ out) {
  int i = blockIdx.x * 256 + threadIdx.x;  // 131072 total
  float s = 0;
#pragma unroll
  for (int ns = 0; ns < 8; ++ns) s += part[(size_t)ns * 131072 + i];
  out[i] = s;
}

// ---------------- attention: scores -> softmax -> PV ----------------
// one thread per row n; kvlin: [bh][2][16][64] f32
__global__ void attn_kernel(const unsigned short* __restrict__ qkv,
                            const float* __restrict__ kvlin,
                            unsigned short* __restrict__ aout) {
  __shared__ float kl[1024], vl[1024];
  const int tid = threadIdx.x;
  const int bid = blockIdx.x;  // 1024 = bh*16 + nt
  const int bh = bid >> 4, nt = bid & 15;
  const int b = bh >> 4, h = bh & 15;
  for (int i = tid; i < 1024; i += 256) {
    kl[i] = kvlin[(size_t)bh * 2048 + i];
    vl[i] = kvlin[(size_t)bh * 2048 + 1024 + i];
  }
  __syncthreads();
  const int n = nt * 256 + tid;
  const unsigned short* qp = qkv + (size_t)(b * SEQLEN + n) * 3072 + h * 64;
  float q[64];
#pragma unroll
  for (int c2 = 0; c2 < 8; ++c2) {
    u16x8 v = *reinterpret_cast<const u16x8*>(qp + c2 * 8);
#pragma unroll
    for (int j = 0; j < 8; ++j) q[c2 * 8 + j] = bf2f(v[j]);
  }
  float s[16];
#pragma unroll
  for (int k = 0; k < 16; ++k) {
    float a = 0;
#pragma unroll
    for (int dd = 0; dd < 64; ++dd) a += q[dd] * kl[k * 64 + dd];
    s[k] = a * 0.125f;
  }
  float mx = s[0];
#pragma unroll
  for (int k = 1; k < 16; ++k) mx = fmaxf(mx, s[k]);
  float sum = 0;
#pragma unroll
  for (int k = 0; k < 16; ++k) { s[k] = __expf(s[k] - mx); sum += s[k]; }
  float inv = 1.0f / sum;
#pragma unroll
  for (int k = 0; k < 16; ++k) s[k] *= inv;
  unsigned short* op = aout + (size_t)(b * SEQLEN + n) * 1024 + h * 64;
#pragma unroll
  for (int d0 = 0; d0 < 8; ++d0) {
    float o[8] = {0, 0, 0, 0, 0, 0, 0, 0};
#pragma unroll
    for (int k = 0; k < 16; ++k) {
      float p = s[k];
#pragma unroll
      for (int j = 0; j < 8; ++j) o[j] += p * vl[k * 64 + d0 * 8 + j];
    }
    u16x8 pk;
#pragma unroll
    for (int j = 0; j < 8; ++j) pk[j] = f2bf(o[j]);
    *reinterpret_cast<u16x8*>(op + d0 * 8) = pk;
  }
}

extern "C" void kernel_launch(void* const* d_in, const int* in_sizes, int n_in,
                              void* d_out, int out_size, void* d_ws, size_t ws_size,
                              hipStream_t stream) {
  const float* x  = (const float*)d_in[0];
  const float* Wq = (const float*)d_in[1];
  const float* bq = (const float*)d_in[2];
  const float* Wk = (const float*)d_in[3];
  const float* bk = (const float*)d_in[4];
  const float* Wv = (const float*)d_in[5];
  const float* bv = (const float*)d_in[6];
  const float* Wo = (const float*)d_in[7];
  const float* bo = (const float*)d_in[8];
  const float* E  = (const float*)d_in[9];
  const float* F  = (const float*)d_in[10];
  float* out = (float*)d_out;

  char* ws = (char*)d_ws;
  unsigned short* Xb   = (unsigned short*)(ws);                // 33,554,432 B
  unsigned short* Wqkv = (unsigned short*)(ws + 33554432);     //  6,291,456 B
  unsigned short* WoB  = (unsigned short*)(ws + 39845888);     //  2,097,152 B
  float*          Bqkv = (float*)(ws + 41943040);              //     12,288 B
  unsigned short* QKV  = (unsigned short*)(ws + 41955328);     // 100,663,296 B
  float*          KVp  = (float*)(ws + 142618624);             //  4,194,304 B
  float*          KVl  = (float*)(ws + 146812928);             //    524,288 B
  unsigned short* AOut = Xb;  // x-bf16 dead after QKV GEMM; reuse

  cvt_f32_to_bf16<<<16384, 256, 0, stream>>>(x, Xb, 4194304);
  cvt_f32_to_bf16<<<1024, 256, 0, stream>>>(Wq, Wqkv, 262144);
  cvt_f32_to_bf16<<<1024, 256, 0, stream>>>(Wk, Wqkv + 1048576, 262144);
  cvt_f32_to_bf16<<<1024, 256, 0, stream>>>(Wv, Wqkv + 2097152, 262144);
  cvt_f32_to_bf16<<<1024, 256, 0, stream>>>(Wo, WoB, 262144);
  pack_bias<<<4, 256, 0, stream>>>(bq, bk, bv, Bqkv);

  // QKV = Xb @ Wqkv^T + Bqkv : [16384, 3072] bf16
  gemm_bt<unsigned short><<<dim3(24, 128), 256, 0, stream>>>(
      Xb, Wqkv, Bqkv, QKV, 16384, 3072, 1024, 3072);

  kvlin_part<<<512, 256, 0, stream>>>(QKV, E, F, KVp);
  kvlin_reduce<<<512, 256, 0, stream>>>(KVp, KVl);
  attn_kernel<<<1024, 256, 0, stream>>>(QKV, KVl, AOut);

  // out = AOut @ Wo^T + bo : [16384, 1024] f32
  gemm_bt<float><<<dim3(8, 128), 256, 0, stream>>>(
      AOut, WoB, bo, out, 16384, 1024, 1024, 1024);
}

// Round 3
// 275.846 us; speedup vs baseline: 1.0216x; 1.0216x over previous
//
#include <hip/hip_runtime.h>
#include <hip/hip_bf16.h>

#define SEQLEN 4096

typedef __bf16 bf16x8 __attribute__((ext_vector_type(8)));
typedef float f32x4 __attribute__((ext_vector_type(4)));
typedef __attribute__((ext_vector_type(8))) unsigned short u16x8;

__device__ inline float bf2f(unsigned short s) {
  union { unsigned u; float f; } t; t.u = ((unsigned)s) << 16; return t.f;
}
__device__ inline unsigned short f2bf(float f) {
  __hip_bfloat16 h = __float2bfloat16(f);
  return *reinterpret_cast<unsigned short*>(&h);
}

__device__ inline void gload_lds16(const void* g, void* l) {
  __builtin_amdgcn_global_load_lds(
      (const __attribute__((address_space(1))) unsigned int*)g,
      (__attribute__((address_space(3))) unsigned int*)l, 16, 0, 0);
}

// ---------------- conversion kernels ----------------
__global__ void cvt_f32_to_bf16(const float* __restrict__ s,
                                unsigned short* __restrict__ d, int n4) {
  int i = blockIdx.x * 256 + threadIdx.x;
  if (i >= n4) return;
  float4 v = reinterpret_cast<const float4*>(s)[i];
  ushort4 o;
  o.x = f2bf(v.x); o.y = f2bf(v.y); o.z = f2bf(v.z); o.w = f2bf(v.w);
  reinterpret_cast<ushort4*>(d)[i] = o;
}

__global__ void pack_bias(const float* __restrict__ a, const float* __restrict__ b,
                          const float* __restrict__ c, float* __restrict__ dst) {
  int i = blockIdx.x * 256 + threadIdx.x;
  if (i < 1024) { dst[i] = a[i]; dst[1024 + i] = b[i]; dst[2048 + i] = c[i]; }
}

// ---------------- 256x256 8-phase bf16 GEMM: C = A @ B^T + bias ----------------
// A: [M][K] bf16, B: [N][K] bf16 (torch weight layout). 512 threads = 8 waves
// (2M x 4N). BK=64, double-buffered 128 KiB LDS, counted vmcnt, raw barriers.
// LDS granule swizzle: slot (row, g) holds global (row, g ^ (row&7)); staged via
// pre-swizzled global source (linear global_load_lds dest), read with same XOR.

#define MFMA16(mk, A00, A01, A10, A11)                                          \
  __builtin_amdgcn_s_setprio(1);                                                \
  _Pragma("unroll")                                                             \
  for (int n = 0; n < 4; ++n) {                                                 \
    acc[2*(mk)][n]   = __builtin_amdgcn_mfma_f32_16x16x32_bf16(A00, b[n][0], acc[2*(mk)][n],   0, 0, 0); \
    acc[2*(mk)][n]   = __builtin_amdgcn_mfma_f32_16x16x32_bf16(A01, b[n][1], acc[2*(mk)][n],   0, 0, 0); \
    acc[2*(mk)+1][n] = __builtin_amdgcn_mfma_f32_16x16x32_bf16(A10, b[n][0], acc[2*(mk)+1][n], 0, 0, 0); \
    acc[2*(mk)+1][n] = __builtin_amdgcn_mfma_f32_16x16x32_bf16(A11, b[n][1], acc[2*(mk)+1][n], 0, 0, 0); \
  }                                                                             \
  __builtin_amdgcn_s_setprio(0);

#define LDA8(mi, sg) (*reinterpret_cast<const bf16x8*>(&as[((wr << 7) + (mi) * 16 + r16) * 64 + (sg) * 8]))
#define LDB8(ni, sg) (*reinterpret_cast<const bf16x8*>(&bs[((wc << 6) + (ni) * 16 + r16) * 64 + (sg) * 8]))

template <typename OUT_T>
__global__ __launch_bounds__(512, 2) void gemm8p(
    const unsigned short* __restrict__ A, const unsigned short* __restrict__ B,
    const float* __restrict__ bias, OUT_T* __restrict__ C, int M, int N, int K,
    int ldc) {
  extern __shared__ __align__(16) unsigned short lds[];
  // layout: A buf0 @0, A buf1 @16384, B buf0 @32768, B buf1 @49152 (ushort idx)

  const int tid = threadIdx.x;
  const int lane = tid & 63, wv = tid >> 6;
  const int wr = wv >> 2, wc = wv & 3;
  const int r16 = lane & 15, kg = lane >> 4;
  const int sg0 = (0 * 4 + kg) ^ (r16 & 7);
  const int sg1 = (1 * 4 + kg) ^ (r16 & 7);

  // bijective XCD swizzle (gridDim.x % 8 == 0 guaranteed by launcher)
  const int nwg = gridDim.x;
  const int cpx = nwg >> 3;
  const int swz = ((int)blockIdx.x & 7) * cpx + ((int)blockIdx.x >> 3);
  const int mt = M >> 8;
  const int tile_m = swz % mt, tile_n = swz / mt;
  const int brow = tile_m << 8, bcol = tile_n << 8;

  const unsigned short* Ag = A + (size_t)brow * K;
  const unsigned short* Bg = B + (size_t)bcol * K;

  const int sr = tid >> 3;                 // staging row within 64-row chunk
  const int sc = tid & 7;                  // staging granule (linear LDS dest)
  const int sgl = sc ^ (sr & 7);           // pre-swizzled global granule

  auto STG = [&](const unsigned short* G, unsigned short* dstbuf, int row0, int kt) {
    gload_lds16(G + (size_t)(row0 + sr) * K + (size_t)kt * 64 + sgl * 8,
                dstbuf + (row0 + sr) * 64 + sc * 8);
  };

  f32x4 acc[8][4];
#pragma unroll
  for (int m = 0; m < 8; ++m)
#pragma unroll
    for (int n = 0; n < 4; ++n) acc[m][n] = (f32x4)0.0f;

  // prologue: stage tile 0 (SA0, SB0, SB1, SA1), drain first 3 stages
  {
    unsigned short* a0 = lds;
    unsigned short* b0 = lds + 32768;
    STG(Ag, a0, 0, 0);   STG(Ag, a0, 128, 0);
    STG(Bg, b0, 0, 0);   STG(Bg, b0, 64, 0);
    STG(Bg, b0, 128, 0); STG(Bg, b0, 192, 0);
    STG(Ag, a0, 64, 0);  STG(Ag, a0, 192, 0);
  }
  asm volatile("s_waitcnt vmcnt(2)" ::: "memory");
  __builtin_amdgcn_s_barrier();

  const int NT = K >> 6;
  for (int t = 0; t < NT; ++t) {
    const int cur = t & 1;
    const unsigned short* as = lds + (cur << 14);
    const unsigned short* bs = lds + 32768 + (cur << 14);
    unsigned short* an = lds + ((cur ^ 1) << 14);
    unsigned short* bn = lds + 32768 + ((cur ^ 1) << 14);
    const int tn = (t + 1 < NT) ? t + 1 : 0;  // clamp keeps vmcnt ledger uniform

    bf16x8 b[4][2];
#pragma unroll
    for (int n = 0; n < 4; ++n) { b[n][0] = LDB8(n, sg0); b[n][1] = LDB8(n, sg1); }

    // ---- phase 0: mfrags 0,1 ; stage SA0(next)
    {
      bf16x8 a00 = LDA8(0, sg0), a01 = LDA8(0, sg1);
      bf16x8 a10 = LDA8(1, sg0), a11 = LDA8(1, sg1);
      STG(Ag, an, 0, tn); STG(Ag, an, 128, tn);
      __builtin_amdgcn_s_barrier();
      MFMA16(0, a00, a01, a10, a11);
      __builtin_amdgcn_s_barrier();
    }
    // ---- phase 1: mfrags 2,3 ; stage SB0(next) ; drain SA1(cur)
    {
      bf16x8 a00 = LDA8(2, sg0), a01 = LDA8(2, sg1);
      bf16x8 a10 = LDA8(3, sg0), a11 = LDA8(3, sg1);
      STG(Bg, bn, 0, tn); STG(Bg, bn, 64, tn);
      __builtin_amdgcn_s_barrier();
      MFMA16(1, a00, a01, a10, a11);
      asm volatile("s_waitcnt vmcnt(4)" ::: "memory");
      __builtin_amdgcn_s_barrier();
    }
    // ---- phase 2: mfrags 4,5 ; stage SB1(next)
    {
      bf16x8 a00 = LDA8(4, sg0), a01 = LDA8(4, sg1);
      bf16x8 a10 = LDA8(5, sg0), a11 = LDA8(5, sg1);
      STG(Bg, bn, 128, tn); STG(Bg, bn, 192, tn);
      __builtin_amdgcn_s_barrier();
      MFMA16(2, a00, a01, a10, a11);
      __builtin_amdgcn_s_barrier();
    }
    // ---- phase 3: mfrags 6,7 ; stage SA1(next) ; drain SA0/SB0/SB1(next)
    {
      bf16x8 a00 = LDA8(6, sg0), a01 = LDA8(6, sg1);
      bf16x8 a10 = LDA8(7, sg0), a11 = LDA8(7, sg1);
      STG(Ag, an, 64, tn); STG(Ag, an, 192, tn);
      __builtin_amdgcn_s_barrier();
      MFMA16(3, a00, a01, a10, a11);
      asm volatile("s_waitcnt vmcnt(2)" ::: "memory");
      __builtin_amdgcn_s_barrier();
    }
  }
  asm volatile("s_waitcnt vmcnt(0)" ::: "memory");

  // epilogue
#pragma unroll
  for (int n = 0; n < 4; ++n) {
    int col = bcol + wc * 64 + n * 16 + r16;
    float bv = bias ? bias[col] : 0.0f;
#pragma unroll
    for (int m = 0; m < 8; ++m) {
#pragma unroll
      for (int r = 0; r < 4; ++r) {
        int row = brow + wr * 128 + m * 16 + kg * 4 + r;
        float v = acc[m][n][r] + bv;
        if constexpr (sizeof(OUT_T) == 2) {
          C[(size_t)row * ldc + col] = f2bf(v);
        } else {
          C[(size_t)row * ldc + col] = v;
        }
      }
    }
  }
}

// ---------------- k_lin / v_lin partial sums ----------------
__global__ void kvlin_part(const unsigned short* __restrict__ qkv,
                           const float* __restrict__ E, const float* __restrict__ F,
                           float* __restrict__ part) {
  __shared__ __align__(16) unsigned short Ks[128 * 64], Vs[128 * 64];
  __shared__ __align__(16) float Es[16 * 128], Fs[16 * 128];
  const int tid = threadIdx.x;
  const int bid = blockIdx.x;
  const int bh = bid >> 3, ns = bid & 7;
  const int b = bh >> 4, h = bh & 15;
  const int d = tid & 63, kk = tid >> 6;
  float aK[4] = {0, 0, 0, 0}, aV[4] = {0, 0, 0, 0};
  for (int c = 0; c < 4; ++c) {
    int n0 = ns * 512 + c * 128;
#pragma unroll
    for (int it = 0; it < 4; ++it) {
      int f = it * 256 + tid;
      int row = f >> 3, ch = f & 7;
      const unsigned short* gk =
          qkv + (size_t)(b * SEQLEN + n0 + row) * 3072 + 1024 + h * 64 + ch * 8;
      gload_lds16(gk, &Ks[f * 8]);
      gload_lds16(gk + 1024, &Vs[f * 8]);
    }
#pragma unroll
    for (int it = 0; it < 2; ++it) {
      int f = it * 256 + tid;
      int k = f >> 5, ch = f & 31;
      const float* ge = E + (size_t)(h * 16 + k) * SEQLEN + n0 + ch * 4;
      const float* gf = F + (size_t)(h * 16 + k) * SEQLEN + n0 + ch * 4;
      gload_lds16(ge, &Es[f * 4]);
      gload_lds16(gf, &Fs[f * 4]);
    }
    __syncthreads();
    for (int n = 0; n < 128; ++n) {
      float kv = bf2f(Ks[n * 64 + d]);
      float vv = bf2f(Vs[n * 64 + d]);
#pragma unroll
      for (int j = 0; j < 4; ++j) {
        aK[j] += Es[(kk * 4 + j) * 128 + n] * kv;
        aV[j] += Fs[(kk * 4 + j) * 128 + n] * vv;
      }
    }
    __syncthreads();
  }
  size_t base = ((size_t)ns * 64 + bh) * 2048;
#pragma unroll
  for (int j = 0; j < 4; ++j) {
    part[base + (kk * 4 + j) * 64 + d] = aK[j];
    part[base + 1024 + (kk * 4 + j) * 64 + d] = aV[j];
  }
}

__global__ void kvlin_reduce(const float* __restrict__ part, float* __restrict__ out) {
  int i = blockIdx.x * 256 + threadIdx.x;
  float s = 0;
#pragma unroll
  for (int ns = 0; ns < 8; ++ns) s += part[(size_t)ns * 131072 + i];
  out[i] = s;
}

// ---------------- attention: scores -> softmax -> PV ----------------
__global__ void attn_kernel(const unsigned short* __restrict__ qkv,
                            const float* __restrict__ kvlin,
                            unsigned short* __restrict__ aout) {
  __shared__ float kl[1024], vl[1024];
  const int tid = threadIdx.x;
  const int bid = blockIdx.x;
  const int bh = bid >> 4, nt = bid & 15;
  const int b = bh >> 4, h = bh & 15;
  for (int i = tid; i < 1024; i += 256) {
    kl[i] = kvlin[(size_t)bh * 2048 + i];
    vl[i] = kvlin[(size_t)bh * 2048 + 1024 + i];
  }
  __syncthreads();
  const int n = nt * 256 + tid;
  const unsigned short* qp = qkv + (size_t)(b * SEQLEN + n) * 3072 + h * 64;
  float q[64];
#pragma unroll
  for (int c2 = 0; c2 < 8; ++c2) {
    u16x8 v = *reinterpret_cast<const u16x8*>(qp + c2 * 8);
#pragma unroll
    for (int j = 0; j < 8; ++j) q[c2 * 8 + j] = bf2f(v[j]);
  }
  float s[16];
#pragma unroll
  for (int k = 0; k < 16; ++k) {
    float a = 0;
#pragma unroll
    for (int dd = 0; dd < 64; ++dd) a += q[dd] * kl[k * 64 + dd];
    s[k] = a * 0.125f;
  }
  float mx = s[0];
#pragma unroll
  for (int k = 1; k < 16; ++k) mx = fmaxf(mx, s[k]);
  float sum = 0;
#pragma unroll
  for (int k = 0; k < 16; ++k) { s[k] = __expf(s[k] - mx); sum += s[k]; }
  float inv = 1.0f / sum;
#pragma unroll
  for (int k = 0; k < 16; ++k) s[k] *= inv;
  unsigned short* op = aout + (size_t)(b * SEQLEN + n) * 1024 + h * 64;
#pragma unroll
  for (int d0 = 0; d0 < 8; ++d0) {
    float o[8] = {0, 0, 0, 0, 0, 0, 0, 0};
#pragma unroll
    for (int k = 0; k < 16; ++k) {
      float p = s[k];
#pragma unroll
      for (int j = 0; j < 8; ++j) o[j] += p * vl[k * 64 + d0 * 8 + j];
    }
    u16x8 pk;
#pragma unroll
    for (int j = 0; j < 8; ++j) pk[j] = f2bf(o[j]);
    *reinterpret_cast<u16x8*>(op + d0 * 8) = pk;
  }
}

extern "C" void kernel_launch(void* const* d_in, const int* in_sizes, int n_in,
                              void* d_out, int out_size, void* d_ws, size_t ws_size,
                              hipStream_t stream) {
  const float* x  = (const float*)d_in[0];
  const float* Wq = (const float*)d_in[1];
  const float* bq = (const float*)d_in[2];
  const float* Wk = (const float*)d_in[3];
  const float* bk = (const float*)d_in[4];
  const float* Wv = (const float*)d_in[5];
  const float* bv = (const float*)d_in[6];
  const float* Wo = (const float*)d_in[7];
  const float* bo = (const float*)d_in[8];
  const float* E  = (const float*)d_in[9];
  const float* F  = (const float*)d_in[10];
  float* out = (float*)d_out;

  char* ws = (char*)d_ws;
  unsigned short* Xb   = (unsigned short*)(ws);                // 33,554,432 B
  unsigned short* Wqkv = (unsigned short*)(ws + 33554432);     //  6,291,456 B
  unsigned short* WoB  = (unsigned short*)(ws + 39845888);     //  2,097,152 B
  float*          Bqkv = (float*)(ws + 41943040);              //     12,288 B
  unsigned short* QKV  = (unsigned short*)(ws + 41955328);     // 100,663,296 B
  float*          KVp  = (float*)(ws + 142618624);             //  4,194,304 B
  float*          KVl  = (float*)(ws + 146812928);             //    524,288 B
  unsigned short* AOut = Xb;  // x-bf16 dead after QKV GEMM; reuse

  (void)hipFuncSetAttribute(reinterpret_cast<const void*>(gemm8p<unsigned short>),
                            hipFuncAttributeMaxDynamicSharedMemorySize, 131072);
  (void)hipFuncSetAttribute(reinterpret_cast<const void*>(gemm8p<float>),
                            hipFuncAttributeMaxDynamicSharedMemorySize, 131072);

  cvt_f32_to_bf16<<<16384, 256, 0, stream>>>(x, Xb, 4194304);
  cvt_f32_to_bf16<<<1024, 256, 0, stream>>>(Wq, Wqkv, 262144);
  cvt_f32_to_bf16<<<1024, 256, 0, stream>>>(Wk, Wqkv + 1048576, 262144);
  cvt_f32_to_bf16<<<1024, 256, 0, stream>>>(Wv, Wqkv + 2097152, 262144);
  cvt_f32_to_bf16<<<1024, 256, 0, stream>>>(Wo, WoB, 262144);
  pack_bias<<<4, 256, 0, stream>>>(bq, bk, bv, Bqkv);

  // QKV = Xb @ Wqkv^T + Bqkv : [16384, 3072] bf16 ; 64x12=768 tiles
  gemm8p<unsigned short><<<768, 512, 131072, stream>>>(
      Xb, Wqkv, Bqkv, QKV, 16384, 3072, 1024, 3072);

  kvlin_part<<<512, 256, 0, stream>>>(QKV, E, F, KVp);
  kvlin_reduce<<<512, 256, 0, stream>>>(KVp, KVl);
  attn_kernel<<<1024, 256, 0, stream>>>(QKV, KVl, AOut);

  // out = AOut @ Wo^T + bo : [16384, 1024] f32 ; 64x4=256 tiles
  gemm8p<float><<<256, 512, 131072, stream>>>(
      AOut, WoB, bo, out, 16384, 1024, 1024, 1024);
}

// Round 4
// 266.788 us; speedup vs baseline: 1.0563x; 1.0340x over previous
//
#include <hip/hip_runtime.h>
#include <hip/hip_bf16.h>

#define SEQLEN 4096

typedef __bf16 bf16x8 __attribute__((ext_vector_type(8)));
typedef float f32x4 __attribute__((ext_vector_type(4)));
typedef __attribute__((ext_vector_type(8))) unsigned short u16x8;

__device__ inline float bf2f(unsigned short s) {
  union { unsigned u; float f; } t; t.u = ((unsigned)s) << 16; return t.f;
}
__device__ inline unsigned short f2bf(float f) {
  __hip_bfloat16 h = __float2bfloat16(f);
  return *reinterpret_cast<unsigned short*>(&h);
}

__device__ inline void gload_lds16(const void* g, void* l) {
  __builtin_amdgcn_global_load_lds(
      (const __attribute__((address_space(1))) unsigned int*)g,
      (__attribute__((address_space(3))) unsigned int*)l, 16, 0, 0);
}

// ---------------- conversion kernels ----------------
__global__ void cvt_f32_to_bf16(const float* __restrict__ s,
                                unsigned short* __restrict__ d, int n4) {
  int i = blockIdx.x * 256 + threadIdx.x;
  if (i >= n4) return;
  float4 v = reinterpret_cast<const float4*>(s)[i];
  ushort4 o;
  o.x = f2bf(v.x); o.y = f2bf(v.y); o.z = f2bf(v.z); o.w = f2bf(v.w);
  reinterpret_cast<ushort4*>(d)[i] = o;
}

__global__ void pack_bias(const float* __restrict__ a, const float* __restrict__ b,
                          const float* __restrict__ c, float* __restrict__ dst) {
  int i = blockIdx.x * 256 + threadIdx.x;
  if (i < 1024) { dst[i] = a[i]; dst[1024 + i] = b[i]; dst[2048 + i] = c[i]; }
}

// ---------------- 256x256 8-phase bf16 GEMM: C = A @ B^T + bias ----------------
// 512 threads = 8 waves (2M x 4N). BK=64, double-buffered 128 KiB LDS, counted
// vmcnt (B staged 3 phases ahead, A >=2), raw barriers, granule XOR swizzle.

#define MFMA16(mk, A00, A01, A10, A11)                                          \
  __builtin_amdgcn_s_setprio(1);                                                \
  _Pragma("unroll")                                                             \
  for (int n = 0; n < 4; ++n) {                                                 \
    acc[2*(mk)][n]   = __builtin_amdgcn_mfma_f32_16x16x32_bf16(A00, b[n][0], acc[2*(mk)][n],   0, 0, 0); \
    acc[2*(mk)][n]   = __builtin_amdgcn_mfma_f32_16x16x32_bf16(A01, b[n][1], acc[2*(mk)][n],   0, 0, 0); \
    acc[2*(mk)+1][n] = __builtin_amdgcn_mfma_f32_16x16x32_bf16(A10, b[n][0], acc[2*(mk)+1][n], 0, 0, 0); \
    acc[2*(mk)+1][n] = __builtin_amdgcn_mfma_f32_16x16x32_bf16(A11, b[n][1], acc[2*(mk)+1][n], 0, 0, 0); \
  }                                                                             \
  __builtin_amdgcn_s_setprio(0);

#define LDA8(mi, sg) (*reinterpret_cast<const bf16x8*>(&as[((wr << 7) + (mi) * 16 + r16) * 64 + (sg) * 8]))
#define LDB8(ni, sg) (*reinterpret_cast<const bf16x8*>(&bs[((wc << 6) + (ni) * 16 + r16) * 64 + (sg) * 8]))

template <typename OUT_T>
__global__ __launch_bounds__(512, 2) void gemm8p(
    const unsigned short* __restrict__ A, const unsigned short* __restrict__ B,
    const float* __restrict__ bias, OUT_T* __restrict__ C, int M, int N, int K,
    int ldc) {
  extern __shared__ __align__(16) unsigned short lds[];
  // layout: A buf0 @0, A buf1 @16384, B buf0 @32768, B buf1 @49152 (ushort idx)

  const int tid = threadIdx.x;
  const int lane = tid & 63, wv = tid >> 6;
  const int wr = wv >> 2, wc = wv & 3;
  const int r16 = lane & 15, kg = lane >> 4;
  const int sg0 = (0 * 4 + kg) ^ (r16 & 7);
  const int sg1 = (1 * 4 + kg) ^ (r16 & 7);

  // bijective XCD swizzle (gridDim.x % 8 == 0 guaranteed by launcher)
  const int nwg = gridDim.x;
  const int cpx = nwg >> 3;
  const int swz = ((int)blockIdx.x & 7) * cpx + ((int)blockIdx.x >> 3);
  const int mt = M >> 8;
  const int tile_m = swz % mt, tile_n = swz / mt;
  const int brow = tile_m << 8, bcol = tile_n << 8;

  const unsigned short* Ag = A + (size_t)brow * K;
  const unsigned short* Bg = B + (size_t)bcol * K;

  const int sr = tid >> 3;                 // staging row within 64-row chunk
  const int sc = tid & 7;                  // staging granule (linear LDS dest)
  const int sgl = sc ^ (sr & 7);           // pre-swizzled global granule

  auto STG = [&](const unsigned short* G, unsigned short* dstbuf, int row0, int kt) {
    gload_lds16(G + (size_t)(row0 + sr) * K + (size_t)kt * 64 + sgl * 8,
                dstbuf + (row0 + sr) * 64 + sc * 8);
  };

  f32x4 acc[8][4];
#pragma unroll
  for (int m = 0; m < 8; ++m)
#pragma unroll
    for (int n = 0; n < 4; ++n) acc[m][n] = (f32x4)0.0f;

  // prologue: B(0) x4, SA0(0) x2, SA1(0) x2; drain oldest 6
  {
    unsigned short* a0 = lds;
    unsigned short* b0 = lds + 32768;
    STG(Bg, b0, 0, 0);   STG(Bg, b0, 64, 0);
    STG(Bg, b0, 128, 0); STG(Bg, b0, 192, 0);
    STG(Ag, a0, 0, 0);   STG(Ag, a0, 128, 0);
    STG(Ag, a0, 64, 0);  STG(Ag, a0, 192, 0);
  }
  asm volatile("s_waitcnt vmcnt(2)" ::: "memory");
  __builtin_amdgcn_s_barrier();

  const int NT = K >> 6;
  for (int t = 0; t < NT; ++t) {
    const int cur = t & 1;
    const unsigned short* as = lds + (cur << 14);
    const unsigned short* bs = lds + 32768 + (cur << 14);
    unsigned short* an = lds + ((cur ^ 1) << 14);
    unsigned short* bn = lds + 32768 + ((cur ^ 1) << 14);
    const int tn = (t + 1 < NT) ? t + 1 : 0;  // clamp keeps vmcnt ledger uniform

    bf16x8 b[4][2];
#pragma unroll
    for (int n = 0; n < 4; ++n) { b[n][0] = LDB8(n, sg0); b[n][1] = LDB8(n, sg1); }

    // ---- phase 0: mfrags 0,1 ; stage SB all 4 chunks (3-phase slack)
    {
      bf16x8 a00 = LDA8(0, sg0), a01 = LDA8(0, sg1);
      bf16x8 a10 = LDA8(1, sg0), a11 = LDA8(1, sg1);
      STG(Bg, bn, 0, tn);   STG(Bg, bn, 64, tn);
      STG(Bg, bn, 128, tn); STG(Bg, bn, 192, tn);
      __builtin_amdgcn_s_barrier();
      MFMA16(0, a00, a01, a10, a11);
      __builtin_amdgcn_s_barrier();
    }
    // ---- phase 1: mfrags 2,3 ; stage SA0(next) ; drain SA1(cur) (issued 3 phases ago)
    {
      bf16x8 a00 = LDA8(2, sg0), a01 = LDA8(2, sg1);
      bf16x8 a10 = LDA8(3, sg0), a11 = LDA8(3, sg1);
      STG(Ag, an, 0, tn); STG(Ag, an, 128, tn);
      __builtin_amdgcn_s_barrier();
      MFMA16(1, a00, a01, a10, a11);
      asm volatile("s_waitcnt vmcnt(6)" ::: "memory");
      __builtin_amdgcn_s_barrier();
    }
    // ---- phase 2: mfrags 4,5 ; stage SA1(next)
    {
      bf16x8 a00 = LDA8(4, sg0), a01 = LDA8(4, sg1);
      bf16x8 a10 = LDA8(5, sg0), a11 = LDA8(5, sg1);
      STG(Ag, an, 64, tn); STG(Ag, an, 192, tn);
      __builtin_amdgcn_s_barrier();
      MFMA16(2, a00, a01, a10, a11);
      __builtin_amdgcn_s_barrier();
    }
    // ---- phase 3: mfrags 6,7 ; drain SB(next)+SA0(next) (oldest 6)
    {
      bf16x8 a00 = LDA8(6, sg0), a01 = LDA8(6, sg1);
      bf16x8 a10 = LDA8(7, sg0), a11 = LDA8(7, sg1);
      __builtin_amdgcn_s_barrier();
      MFMA16(3, a00, a01, a10, a11);
      asm volatile("s_waitcnt vmcnt(2)" ::: "memory");
      __builtin_amdgcn_s_barrier();
    }
  }
  asm volatile("s_waitcnt vmcnt(0)" ::: "memory");

  // epilogue
  if constexpr (sizeof(OUT_T) == 2) {
    // LDS-staged vectorized bf16 stores (full 64B sectors, no RMW)
    __builtin_amdgcn_s_barrier();  // all waves' DMA landed before LDS reuse
    unsigned short* C2 = reinterpret_cast<unsigned short*>(C);
    float bvs[4];
#pragma unroll
    for (int n = 0; n < 4; ++n)
      bvs[n] = bias ? bias[bcol + wc * 64 + n * 16 + r16] : 0.0f;
#pragma unroll
    for (int m = 0; m < 8; ++m) {
#pragma unroll
      for (int r = 0; r < 4; ++r) {
        int rw = m * 16 + kg * 4 + r;
        int xo = (rw & 12) << 2;  // kg-XOR on element-col bits 4-5
#pragma unroll
        for (int n = 0; n < 4; ++n) {
          lds[wv * 8192 + rw * 64 + ((n * 16 + r16) ^ xo)] =
              f2bf(acc[m][n][r] + bvs[n]);
        }
      }
    }
    __syncthreads();
#pragma unroll
    for (int p = 0; p < 16; ++p) {
      int grow = p * 16 + (tid >> 5);
      int g = tid & 31;                       // 16B granule across 256 cols
      int wvs = ((grow >> 7) << 2) + (g >> 3);
      int row_l = grow & 127;
      int src = wvs * 8192 + row_l * 64 + (((g & 7) * 8) ^ ((row_l & 12) << 2));
      u16x8 vv = *reinterpret_cast<const u16x8*>(&lds[src]);
      *reinterpret_cast<u16x8*>(&C2[(size_t)(brow + grow) * ldc + bcol + g * 8]) = vv;
    }
  } else {
#pragma unroll
    for (int n = 0; n < 4; ++n) {
      int col = bcol + wc * 64 + n * 16 + r16;
      float bv = bias ? bias[col] : 0.0f;
#pragma unroll
      for (int m = 0; m < 8; ++m) {
#pragma unroll
        for (int r = 0; r < 4; ++r) {
          int row = brow + wr * 128 + m * 16 + kg * 4 + r;
          C[(size_t)row * ldc + col] = acc[m][n][r] + bv;
        }
      }
    }
  }
}

// ---------------- k_lin / v_lin partial sums ----------------
__global__ void kvlin_part(const unsigned short* __restrict__ qkv,
                           const float* __restrict__ E, const float* __restrict__ F,
                           float* __restrict__ part) {
  __shared__ __align__(16) unsigned short Ks[128 * 64], Vs[128 * 64];
  __shared__ __align__(16) float Es[16 * 128], Fs[16 * 128];
  const int tid = threadIdx.x;
  const int bid = blockIdx.x;
  const int bh = bid >> 3, ns = bid & 7;
  const int b = bh >> 4, h = bh & 15;
  const int d = tid & 63, kk = tid >> 6;
  float aK[4] = {0, 0, 0, 0}, aV[4] = {0, 0, 0, 0};
  for (int c = 0; c < 4; ++c) {
    int n0 = ns * 512 + c * 128;
#pragma unroll
    for (int it = 0; it < 4; ++it) {
      int f = it * 256 + tid;
      int row = f >> 3, ch = f & 7;
      const unsigned short* gk =
          qkv + (size_t)(b * SEQLEN + n0 + row) * 3072 + 1024 + h * 64 + ch * 8;
      gload_lds16(gk, &Ks[f * 8]);
      gload_lds16(gk + 1024, &Vs[f * 8]);
    }
#pragma unroll
    for (int it = 0; it < 2; ++it) {
      int f = it * 256 + tid;
      int k = f >> 5, ch = f & 31;
      const float* ge = E + (size_t)(h * 16 + k) * SEQLEN + n0 + ch * 4;
      const float* gf = F + (size_t)(h * 16 + k) * SEQLEN + n0 + ch * 4;
      gload_lds16(ge, &Es[f * 4]);
      gload_lds16(gf, &Fs[f * 4]);
    }
    __syncthreads();
    for (int n = 0; n < 128; ++n) {
      float kv = bf2f(Ks[n * 64 + d]);
      float vv = bf2f(Vs[n * 64 + d]);
#pragma unroll
      for (int j = 0; j < 4; ++j) {
        aK[j] += Es[(kk * 4 + j) * 128 + n] * kv;
        aV[j] += Fs[(kk * 4 + j) * 128 + n] * vv;
      }
    }
    __syncthreads();
  }
  size_t base = ((size_t)ns * 64 + bh) * 2048;
#pragma unroll
  for (int j = 0; j < 4; ++j) {
    part[base + (kk * 4 + j) * 64 + d] = aK[j];
    part[base + 1024 + (kk * 4 + j) * 64 + d] = aV[j];
  }
}

__global__ void kvlin_reduce(const float* __restrict__ part, float* __restrict__ out) {
  int i = blockIdx.x * 256 + threadIdx.x;
  float s = 0;
#pragma unroll
  for (int ns = 0; ns < 8; ++ns) s += part[(size_t)ns * 131072 + i];
  out[i] = s;
}

// ---------------- attention: scores -> softmax -> PV ----------------
__global__ void attn_kernel(const unsigned short* __restrict__ qkv,
                            const float* __restrict__ kvlin,
                            unsigned short* __restrict__ aout) {
  __shared__ float kl[1024], vl[1024];
  const int tid = threadIdx.x;
  const int bid = blockIdx.x;
  const int bh = bid >> 4, nt = bid & 15;
  const int b = bh >> 4, h = bh & 15;
  for (int i = tid; i < 1024; i += 256) {
    kl[i] = kvlin[(size_t)bh * 2048 + i];
    vl[i] = kvlin[(size_t)bh * 2048 + 1024 + i];
  }
  __syncthreads();
  const int n = nt * 256 + tid;
  const unsigned short* qp = qkv + (size_t)(b * SEQLEN + n) * 3072 + h * 64;
  float q[64];
#pragma unroll
  for (int c2 = 0; c2 < 8; ++c2) {
    u16x8 v = *reinterpret_cast<const u16x8*>(qp + c2 * 8);
#pragma unroll
    for (int j = 0; j < 8; ++j) q[c2 * 8 + j] = bf2f(v[j]);
  }
  float s[16];
#pragma unroll
  for (int k = 0; k < 16; ++k) {
    float a = 0;
#pragma unroll
    for (int dd = 0; dd < 64; ++dd) a += q[dd] * kl[k * 64 + dd];
    s[k] = a * 0.125f;
  }
  float mx = s[0];
#pragma unroll
  for (int k = 1; k < 16; ++k) mx = fmaxf(mx, s[k]);
  float sum = 0;
#pragma unroll
  for (int k = 0; k < 16; ++k) { s[k] = __expf(s[k] - mx); sum += s[k]; }
  float inv = 1.0f / sum;
#pragma unroll
  for (int k = 0; k < 16; ++k) s[k] *= inv;
  unsigned short* op = aout + (size_t)(b * SEQLEN + n) * 1024 + h * 64;
#pragma unroll
  for (int d0 = 0; d0 < 8; ++d0) {
    float o[8] = {0, 0, 0, 0, 0, 0, 0, 0};
#pragma unroll
    for (int k = 0; k < 16; ++k) {
      float p = s[k];
#pragma unroll
      for (int j = 0; j < 8; ++j) o[j] += p * vl[k * 64 + d0 * 8 + j];
    }
    u16x8 pk;
#pragma unroll
    for (int j = 0; j < 8; ++j) pk[j] = f2bf(o[j]);
    *reinterpret_cast<u16x8*>(op + d0 * 8) = pk;
  }
}

extern "C" void kernel_launch(void* const* d_in, const int* in_sizes, int n_in,
                              void* d_out, int out_size, void* d_ws, size_t ws_size,
                              hipStream_t stream) {
  const float* x  = (const float*)d_in[0];
  const float* Wq = (const float*)d_in[1];
  const float* bq = (const float*)d_in[2];
  const float* Wk = (const float*)d_in[3];
  const float* bk = (const float*)d_in[4];
  const float* Wv = (const float*)d_in[5];
  const float* bv = (const float*)d_in[6];
  const float* Wo = (const float*)d_in[7];
  const float* bo = (const float*)d_in[8];
  const float* E  = (const float*)d_in[9];
  const float* F  = (const float*)d_in[10];
  float* out = (float*)d_out;

  char* ws = (char*)d_ws;
  unsigned short* Xb   = (unsigned short*)(ws);                // 33,554,432 B
  unsigned short* Wqkv = (unsigned short*)(ws + 33554432);     //  6,291,456 B
  unsigned short* WoB  = (unsigned short*)(ws + 39845888);     //  2,097,152 B
  float*          Bqkv = (float*)(ws + 41943040);              //     12,288 B
  unsigned short* QKV  = (unsigned short*)(ws + 41955328);     // 100,663,296 B
  float*          KVp  = (float*)(ws + 142618624);             //  4,194,304 B
  float*          KVl  = (float*)(ws + 146812928);             //    524,288 B
  unsigned short* AOut = Xb;  // x-bf16 dead after QKV GEMM; reuse

  (void)hipFuncSetAttribute(reinterpret_cast<const void*>(gemm8p<unsigned short>),
                            hipFuncAttributeMaxDynamicSharedMemorySize, 131072);
  (void)hipFuncSetAttribute(reinterpret_cast<const void*>(gemm8p<float>),
                            hipFuncAttributeMaxDynamicSharedMemorySize, 131072);

  cvt_f32_to_bf16<<<16384, 256, 0, stream>>>(x, Xb, 4194304);
  cvt_f32_to_bf16<<<1024, 256, 0, stream>>>(Wq, Wqkv, 262144);
  cvt_f32_to_bf16<<<1024, 256, 0, stream>>>(Wk, Wqkv + 1048576, 262144);
  cvt_f32_to_bf16<<<1024, 256, 0, stream>>>(Wv, Wqkv + 2097152, 262144);
  cvt_f32_to_bf16<<<1024, 256, 0, stream>>>(Wo, WoB, 262144);
  pack_bias<<<4, 256, 0, stream>>>(bq, bk, bv, Bqkv);

  // QKV = Xb @ Wqkv^T + Bqkv : [16384, 3072] bf16 ; 64x12=768 tiles
  gemm8p<unsigned short><<<768, 512, 131072, stream>>>(
      Xb, Wqkv, Bqkv, QKV, 16384, 3072, 1024, 3072);

  kvlin_part<<<512, 256, 0, stream>>>(QKV, E, F, KVp);
  kvlin_reduce<<<512, 256, 0, stream>>>(KVp, KVl);
  attn_kernel<<<1024, 256, 0, stream>>>(QKV, KVl, AOut);

  // out = AOut @ Wo^T + bo : [16384, 1024] f32 ; 64x4=256 tiles
  gemm8p<float><<<256, 512, 131072, stream>>>(
      AOut, WoB, bo, out, 16384, 1024, 1024, 1024);
}

// Round 5
// 253.386 us; speedup vs baseline: 1.1122x; 1.0529x over previous
//
#include <hip/hip_runtime.h>
#include <hip/hip_bf16.h>

#define SEQLEN 4096

typedef __bf16 bf16x8 __attribute__((ext_vector_type(8)));
typedef float f32x4 __attribute__((ext_vector_type(4)));
typedef __attribute__((ext_vector_type(8))) unsigned short u16x8;

__device__ inline float bf2f(unsigned short s) {
  union { unsigned u; float f; } t; t.u = ((unsigned)s) << 16; return t.f;
}
__device__ inline unsigned short f2bf(float f) {
  __hip_bfloat16 h = __float2bfloat16(f);
  return *reinterpret_cast<unsigned short*>(&h);
}

__device__ inline void gload_lds16(const void* g, void* l) {
  __builtin_amdgcn_global_load_lds(
      (const __attribute__((address_space(1))) unsigned int*)g,
      (__attribute__((address_space(3))) unsigned int*)l, 16, 0, 0);
}

// ---------------- fused conversion kernel ----------------
// float4-granular regions: x | Wq | Wk | Wv | Wo | bias(bq,bk,bv)
__global__ void cvt_all(const float* __restrict__ x, const float* __restrict__ Wq,
                        const float* __restrict__ Wk, const float* __restrict__ Wv,
                        const float* __restrict__ Wo,
                        const float* __restrict__ bq, const float* __restrict__ bk,
                        const float* __restrict__ bv,
                        unsigned short* __restrict__ Xb,
                        unsigned short* __restrict__ Wqkv,
                        unsigned short* __restrict__ WoB, float* __restrict__ Bqkv) {
  long i = (long)blockIdx.x * 256 + threadIdx.x;
  const float* src;
  unsigned short* dst;
  long rel;
  if (i < 4194304) {            // x -> Xb
    src = x; dst = Xb; rel = i;
  } else if (i < 4456448) {     // Wq -> Wqkv[0]
    src = Wq; dst = Wqkv; rel = i - 4194304;
  } else if (i < 4718592) {     // Wk -> Wqkv[1M]
    src = Wk; dst = Wqkv + 1048576; rel = i - 4456448;
  } else if (i < 4980736) {     // Wv -> Wqkv[2M]
    src = Wv; dst = Wqkv + 2097152; rel = i - 4718592;
  } else if (i < 5242880) {     // Wo -> WoB
    src = Wo; dst = WoB; rel = i - 4980736;
  } else if (i < 5243648) {     // bias pack (float4 copy)
    long j = i - 5242880;       // 0..767
    const float* bsrc = (j < 256) ? bq : (j < 512) ? bk : bv;
    long jr = j & 255;
    reinterpret_cast<float4*>(Bqkv)[j] =
        reinterpret_cast<const float4*>(bsrc)[jr];
    return;
  } else {
    return;
  }
  float4 v = reinterpret_cast<const float4*>(src)[rel];
  ushort4 o;
  o.x = f2bf(v.x); o.y = f2bf(v.y); o.z = f2bf(v.z); o.w = f2bf(v.w);
  reinterpret_cast<ushort4*>(dst)[rel] = o;
}

// ---------------- 256x256 8-phase bf16 GEMM: C = A @ B^T + bias ----------------
// 512 threads = 8 waves (2M x 4N). BK=64, double-buffered 128 KiB LDS, counted
// vmcnt (every chunk >=2 phases of slack), raw barriers, granule XOR swizzle.
// XCD 2D chunking: each XCD owns 8 tile_m rows x all tile_n (A set L2-resident).

#define MFMA16(mk, A00, A01, A10, A11)                                          \
  __builtin_amdgcn_s_setprio(1);                                                \
  _Pragma("unroll")                                                             \
  for (int n = 0; n < 4; ++n)                                                   \
    acc[2*(mk)][n]   = __builtin_amdgcn_mfma_f32_16x16x32_bf16(A00, b[n][0], acc[2*(mk)][n],   0, 0, 0); \
  _Pragma("unroll")                                                             \
  for (int n = 0; n < 4; ++n)                                                   \
    acc[2*(mk)+1][n] = __builtin_amdgcn_mfma_f32_16x16x32_bf16(A10, b[n][0], acc[2*(mk)+1][n], 0, 0, 0); \
  _Pragma("unroll")                                                             \
  for (int n = 0; n < 4; ++n)                                                   \
    acc[2*(mk)][n]   = __builtin_amdgcn_mfma_f32_16x16x32_bf16(A01, b[n][1], acc[2*(mk)][n],   0, 0, 0); \
  _Pragma("unroll")                                                             \
  for (int n = 0; n < 4; ++n)                                                   \
    acc[2*(mk)+1][n] = __builtin_amdgcn_mfma_f32_16x16x32_bf16(A11, b[n][1], acc[2*(mk)+1][n], 0, 0, 0); \
  __builtin_amdgcn_s_setprio(0);

#define LDA8(mi, sg) (*reinterpret_cast<const bf16x8*>(&as[((wr << 7) + (mi) * 16 + r16) * 64 + (sg) * 8]))
#define LDB8(ni, sg) (*reinterpret_cast<const bf16x8*>(&bs[((wc << 6) + (ni) * 16 + r16) * 64 + (sg) * 8]))

template <typename OUT_T>
__global__ __launch_bounds__(512, 2) void gemm8p(
    const unsigned short* __restrict__ A, const unsigned short* __restrict__ B,
    const float* __restrict__ bias, OUT_T* __restrict__ C, int M, int N, int K,
    int ldc) {
  extern __shared__ __align__(16) unsigned short lds[];
  // layout: A buf0 @0, A buf1 @16384, B buf0 @32768, B buf1 @49152 (ushort idx)

  const int tid = threadIdx.x;
  const int lane = tid & 63, wv = tid >> 6;
  const int wr = wv >> 2, wc = wv & 3;
  const int r16 = lane & 15, kg = lane >> 4;
  const int sg0 = (0 * 4 + kg) ^ (r16 & 7);
  const int sg1 = (1 * 4 + kg) ^ (r16 & 7);

  // XCD 2D chunk mapping: xcd owns tile_m in [xcd*rpx, (xcd+1)*rpx), col-major
  // (requires (M>>8) % 8 == 0; M=16384 -> rpx=8)
  const int xcd = (int)blockIdx.x & 7;
  const int pos = (int)blockIdx.x >> 3;
  const int rpx = (M >> 8) >> 3;
  const int tile_m = xcd * rpx + (pos % rpx);
  const int tile_n = pos / rpx;
  const int brow = tile_m << 8, bcol = tile_n << 8;

  const unsigned short* Ag = A + (size_t)brow * K;
  const unsigned short* Bg = B + (size_t)bcol * K;

  const int sr = tid >> 3;                 // staging row within 64-row chunk
  const int sc = tid & 7;                  // staging granule (linear LDS dest)
  const int sgl = sc ^ (sr & 7);           // pre-swizzled global granule

  auto STG = [&](const unsigned short* G, unsigned short* dstbuf, int row0, int kt) {
    gload_lds16(G + (size_t)(row0 + sr) * K + (size_t)kt * 64 + sgl * 8,
                dstbuf + (row0 + sr) * 64 + sc * 8);
  };

  f32x4 acc[8][4];
#pragma unroll
  for (int m = 0; m < 8; ++m)
#pragma unroll
    for (int n = 0; n < 4; ++n) acc[m][n] = (f32x4)0.0f;

  // prologue: B(0) x4, SA0(0) x2, SA1(0) x2; drain oldest 6
  {
    unsigned short* a0 = lds;
    unsigned short* b0 = lds + 32768;
    STG(Bg, b0, 0, 0);   STG(Bg, b0, 64, 0);
    STG(Bg, b0, 128, 0); STG(Bg, b0, 192, 0);
    STG(Ag, a0, 0, 0);   STG(Ag, a0, 128, 0);
    STG(Ag, a0, 64, 0);  STG(Ag, a0, 192, 0);
  }
  asm volatile("s_waitcnt vmcnt(2)" ::: "memory");
  __builtin_amdgcn_s_barrier();

  const int NT = K >> 6;
  for (int t = 0; t < NT; ++t) {
    const int cur = t & 1;
    const unsigned short* as = lds + (cur << 14);
    const unsigned short* bs = lds + 32768 + (cur << 14);
    unsigned short* an = lds + ((cur ^ 1) << 14);
    unsigned short* bn = lds + 32768 + ((cur ^ 1) << 14);
    const int tn = (t + 1 < NT) ? t + 1 : 0;  // clamp keeps vmcnt ledger uniform

    bf16x8 b[4][2];
#pragma unroll
    for (int n = 0; n < 4; ++n) { b[n][0] = LDB8(n, sg0); b[n][1] = LDB8(n, sg1); }

    // ---- phase 0: mfrags 0,1 ; stage SB all 4 chunks (3-phase slack)
    {
      bf16x8 a00 = LDA8(0, sg0), a01 = LDA8(0, sg1);
      bf16x8 a10 = LDA8(1, sg0), a11 = LDA8(1, sg1);
      STG(Bg, bn, 0, tn);   STG(Bg, bn, 64, tn);
      STG(Bg, bn, 128, tn); STG(Bg, bn, 192, tn);
      __builtin_amdgcn_s_barrier();
      MFMA16(0, a00, a01, a10, a11);
      __builtin_amdgcn_s_barrier();
    }
    // ---- phase 1: mfrags 2,3 ; stage SA0(next) ; drain SA1(cur) (3-phase slack)
    {
      bf16x8 a00 = LDA8(2, sg0), a01 = LDA8(2, sg1);
      bf16x8 a10 = LDA8(3, sg0), a11 = LDA8(3, sg1);
      STG(Ag, an, 0, tn); STG(Ag, an, 128, tn);
      __builtin_amdgcn_s_barrier();
      MFMA16(1, a00, a01, a10, a11);
      asm volatile("s_waitcnt vmcnt(6)" ::: "memory");
      __builtin_amdgcn_s_barrier();
    }
    // ---- phase 2: mfrags 4,5 ; stage SA1(next)
    {
      bf16x8 a00 = LDA8(4, sg0), a01 = LDA8(4, sg1);
      bf16x8 a10 = LDA8(5, sg0), a11 = LDA8(5, sg1);
      STG(Ag, an, 64, tn); STG(Ag, an, 192, tn);
      __builtin_amdgcn_s_barrier();
      MFMA16(2, a00, a01, a10, a11);
      __builtin_amdgcn_s_barrier();
    }
    // ---- phase 3: mfrags 6,7 ; drain SB(next)+SA0(next) (oldest 6)
    {
      bf16x8 a00 = LDA8(6, sg0), a01 = LDA8(6, sg1);
      bf16x8 a10 = LDA8(7, sg0), a11 = LDA8(7, sg1);
      __builtin_amdgcn_s_barrier();
      MFMA16(3, a00, a01, a10, a11);
      asm volatile("s_waitcnt vmcnt(2)" ::: "memory");
      __builtin_amdgcn_s_barrier();
    }
  }
  asm volatile("s_waitcnt vmcnt(0)" ::: "memory");

  // epilogue
  if constexpr (sizeof(OUT_T) == 2) {
    // LDS-staged vectorized bf16 stores (full 64B sectors, no RMW)
    __builtin_amdgcn_s_barrier();  // all waves' DMA landed before LDS reuse
    unsigned short* C2 = reinterpret_cast<unsigned short*>(C);
    float bvs[4];
#pragma unroll
    for (int n = 0; n < 4; ++n)
      bvs[n] = bias ? bias[bcol + wc * 64 + n * 16 + r16] : 0.0f;
#pragma unroll
    for (int m = 0; m < 8; ++m) {
#pragma unroll
      for (int r = 0; r < 4; ++r) {
        int rw = m * 16 + kg * 4 + r;
        int xo = (rw & 12) << 2;  // kg-XOR on element-col bits 4-5
#pragma unroll
        for (int n = 0; n < 4; ++n) {
          lds[wv * 8192 + rw * 64 + ((n * 16 + r16) ^ xo)] =
              f2bf(acc[m][n][r] + bvs[n]);
        }
      }
    }
    __syncthreads();
#pragma unroll
    for (int p = 0; p < 16; ++p) {
      int grow = p * 16 + (tid >> 5);
      int g = tid & 31;                       // 16B granule across 256 cols
      int wvs = ((grow >> 7) << 2) + (g >> 3);
      int row_l = grow & 127;
      int src = wvs * 8192 + row_l * 64 + (((g & 7) * 8) ^ ((row_l & 12) << 2));
      u16x8 vv = *reinterpret_cast<const u16x8*>(&lds[src]);
      *reinterpret_cast<u16x8*>(&C2[(size_t)(brow + grow) * ldc + bcol + g * 8]) = vv;
    }
  } else {
#pragma unroll
    for (int n = 0; n < 4; ++n) {
      int col = bcol + wc * 64 + n * 16 + r16;
      float bv = bias ? bias[col] : 0.0f;
#pragma unroll
      for (int m = 0; m < 8; ++m) {
#pragma unroll
        for (int r = 0; r < 4; ++r) {
          int row = brow + wr * 128 + m * 16 + kg * 4 + r;
          C[(size_t)row * ldc + col] = acc[m][n][r] + bv;
        }
      }
    }
  }
}

// ---------------- k_lin / v_lin partial sums ----------------
__global__ void kvlin_part(const unsigned short* __restrict__ qkv,
                           const float* __restrict__ E, const float* __restrict__ F,
                           float* __restrict__ part) {
  __shared__ __align__(16) unsigned short Ks[128 * 64], Vs[128 * 64];
  __shared__ __align__(16) float Es[16 * 128], Fs[16 * 128];
  const int tid = threadIdx.x;
  const int bid = blockIdx.x;
  const int bh = bid >> 3, ns = bid & 7;
  const int b = bh >> 4, h = bh & 15;
  const int d = tid & 63, kk = tid >> 6;
  float aK[4] = {0, 0, 0, 0}, aV[4] = {0, 0, 0, 0};
  for (int c = 0; c < 4; ++c) {
    int n0 = ns * 512 + c * 128;
#pragma unroll
    for (int it = 0; it < 4; ++it) {
      int f = it * 256 + tid;
      int row = f >> 3, ch = f & 7;
      const unsigned short* gk =
          qkv + (size_t)(b * SEQLEN + n0 + row) * 3072 + 1024 + h * 64 + ch * 8;
      gload_lds16(gk, &Ks[f * 8]);
      gload_lds16(gk + 1024, &Vs[f * 8]);
    }
#pragma unroll
    for (int it = 0; it < 2; ++it) {
      int f = it * 256 + tid;
      int k = f >> 5, ch = f & 31;
      const float* ge = E + (size_t)(h * 16 + k) * SEQLEN + n0 + ch * 4;
      const float* gf = F + (size_t)(h * 16 + k) * SEQLEN + n0 + ch * 4;
      gload_lds16(ge, &Es[f * 4]);
      gload_lds16(gf, &Fs[f * 4]);
    }
    __syncthreads();
    for (int n = 0; n < 128; ++n) {
      float kv = bf2f(Ks[n * 64 + d]);
      float vv = bf2f(Vs[n * 64 + d]);
#pragma unroll
      for (int j = 0; j < 4; ++j) {
        aK[j] += Es[(kk * 4 + j) * 128 + n] * kv;
        aV[j] += Fs[(kk * 4 + j) * 128 + n] * vv;
      }
    }
    __syncthreads();
  }
  size_t base = ((size_t)ns * 64 + bh) * 2048;
#pragma unroll
  for (int j = 0; j < 4; ++j) {
    part[base + (kk * 4 + j) * 64 + d] = aK[j];
    part[base + 1024 + (kk * 4 + j) * 64 + d] = aV[j];
  }
}

__global__ void kvlin_reduce(const float* __restrict__ part, float* __restrict__ out) {
  int i = blockIdx.x * 256 + threadIdx.x;
  float s = 0;
#pragma unroll
  for (int ns = 0; ns < 8; ++ns) s += part[(size_t)ns * 131072 + i];
  out[i] = s;
}

// ---------------- attention: scores -> softmax -> PV ----------------
__global__ void attn_kernel(const unsigned short* __restrict__ qkv,
                            const float* __restrict__ kvlin,
                            unsigned short* __restrict__ aout) {
  __shared__ float kl[1024], vl[1024];
  const int tid = threadIdx.x;
  const int bid = blockIdx.x;
  const int bh = bid >> 4, nt = bid & 15;
  const int b = bh >> 4, h = bh & 15;
  for (int i = tid; i < 1024; i += 256) {
    kl[i] = kvlin[(size_t)bh * 2048 + i];
    vl[i] = kvlin[(size_t)bh * 2048 + 1024 + i];
  }
  __syncthreads();
  const int n = nt * 256 + tid;
  const unsigned short* qp = qkv + (size_t)(b * SEQLEN + n) * 3072 + h * 64;
  float q[64];
#pragma unroll
  for (int c2 = 0; c2 < 8; ++c2) {
    u16x8 v = *reinterpret_cast<const u16x8*>(qp + c2 * 8);
#pragma unroll
    for (int j = 0; j < 8; ++j) q[c2 * 8 + j] = bf2f(v[j]);
  }
  float s[16];
#pragma unroll
  for (int k = 0; k < 16; ++k) {
    float a = 0;
#pragma unroll
    for (int dd = 0; dd < 64; ++dd) a += q[dd] * kl[k * 64 + dd];
    s[k] = a * 0.125f;
  }
  float mx = s[0];
#pragma unroll
  for (int k = 1; k < 16; ++k) mx = fmaxf(mx, s[k]);
  float sum = 0;
#pragma unroll
  for (int k = 0; k < 16; ++k) { s[k] = __expf(s[k] - mx); sum += s[k]; }
  float inv = 1.0f / sum;
#pragma unroll
  for (int k = 0; k < 16; ++k) s[k] *= inv;
  unsigned short* op = aout + (size_t)(b * SEQLEN + n) * 1024 + h * 64;
#pragma unroll
  for (int d0 = 0; d0 < 8; ++d0) {
    float o[8] = {0, 0, 0, 0, 0, 0, 0, 0};
#pragma unroll
    for (int k = 0; k < 16; ++k) {
      float p = s[k];
#pragma unroll
      for (int j = 0; j < 8; ++j) o[j] += p * vl[k * 64 + d0 * 8 + j];
    }
    u16x8 pk;
#pragma unroll
    for (int j = 0; j < 8; ++j) pk[j] = f2bf(o[j]);
    *reinterpret_cast<u16x8*>(op + d0 * 8) = pk;
  }
}

extern "C" void kernel_launch(void* const* d_in, const int* in_sizes, int n_in,
                              void* d_out, int out_size, void* d_ws, size_t ws_size,
                              hipStream_t stream) {
  const float* x  = (const float*)d_in[0];
  const float* Wq = (const float*)d_in[1];
  const float* bq = (const float*)d_in[2];
  const float* Wk = (const float*)d_in[3];
  const float* bk = (const float*)d_in[4];
  const float* Wv = (const float*)d_in[5];
  const float* bv = (const float*)d_in[6];
  const float* Wo = (const float*)d_in[7];
  const float* bo = (const float*)d_in[8];
  const float* E  = (const float*)d_in[9];
  const float* F  = (const float*)d_in[10];
  float* out = (float*)d_out;

  char* ws = (char*)d_ws;
  unsigned short* Xb   = (unsigned short*)(ws);                // 33,554,432 B
  unsigned short* Wqkv = (unsigned short*)(ws + 33554432);     //  6,291,456 B
  unsigned short* WoB  = (unsigned short*)(ws + 39845888);     //  2,097,152 B
  float*          Bqkv = (float*)(ws + 41943040);              //     12,288 B
  unsigned short* QKV  = (unsigned short*)(ws + 41955328);     // 100,663,296 B
  float*          KVp  = (float*)(ws + 142618624);             //  4,194,304 B
  float*          KVl  = (float*)(ws + 146812928);             //    524,288 B
  unsigned short* AOut = Xb;  // x-bf16 dead after QKV GEMM; reuse

  (void)hipFuncSetAttribute(reinterpret_cast<const void*>(gemm8p<unsigned short>),
                            hipFuncAttributeMaxDynamicSharedMemorySize, 131072);
  (void)hipFuncSetAttribute(reinterpret_cast<const void*>(gemm8p<float>),
                            hipFuncAttributeMaxDynamicSharedMemorySize, 131072);

  // fused f32->bf16 conversions + bias pack: 5243648 float4 units
  cvt_all<<<20483, 256, 0, stream>>>(x, Wq, Wk, Wv, Wo, bq, bk, bv,
                                     Xb, Wqkv, WoB, Bqkv);

  // QKV = Xb @ Wqkv^T + Bqkv : [16384, 3072] bf16 ; 64x12=768 tiles
  gemm8p<unsigned short><<<768, 512, 131072, stream>>>(
      Xb, Wqkv, Bqkv, QKV, 16384, 3072, 1024, 3072);

  kvlin_part<<<512, 256, 0, stream>>>(QKV, E, F, KVp);
  kvlin_reduce<<<512, 256, 0, stream>>>(KVp, KVl);
  attn_kernel<<<1024, 256, 0, stream>>>(QKV, KVl, AOut);

  // out = AOut @ Wo^T + bo : [16384, 1024] f32 ; 64x4=256 tiles
  gemm8p<float><<<256, 512, 131072, stream>>>(
      AOut, WoB, bo, out, 16384, 1024, 1024, 1024);
}